// Round 1
// baseline (386.325 us; speedup 1.0000x reference)
//
#include <hip/hip_runtime.h>
#include <cmath>

#define H     256
#define H3    768
#define L     32
#define STEPS 20
#define VOUT  74
#define NITEMS (L + VOUT)   // 106

// ---- workspace layout (float offsets) ----
// WhhT enc : [64][768] float4  -> 196608 floats
// WhhT dec : [64][768] float4  -> 196608 floats
// fcT      : [64][74]  float4  -> 18944  floats
// ENC_GI   : [32][768] float   -> 24576  floats
// DEC_GI   : [74][768] float   -> 56832  floats
#define WS_WT_ENC 0
#define WS_WT_DEC 196608
#define WS_FCT    393216
#define WS_EGI    412160
#define WS_DGI    436736
// total 493568 floats = ~1.93 MB

// Transpose Whh (both) and fc_W into [kb][row] float4 layout for coalesced
// thread-per-row reads in the sequential kernel.
__global__ void prep_transpose(const float* __restrict__ encWhh,
                               const float* __restrict__ decWhh,
                               const float* __restrict__ fcW,
                               float* __restrict__ ws) {
    int bid = blockIdx.x;
    int l   = threadIdx.x;
    int kb  = l & 63;       // float4 column block 0..63
    int q   = l >> 6;       // 0..3 rows per block
    float4* wtE = (float4*)(ws + WS_WT_ENC);
    float4* wtD = (float4*)(ws + WS_WT_DEC);
    float4* fcT = (float4*)(ws + WS_FCT);
    if (bid < 192) {
        int j = bid * 4 + q;                       // row 0..767
        float4 v = *(const float4*)(encWhh + j * H + kb * 4);
        wtE[kb * H3 + j] = v;
    } else if (bid < 384) {
        int j = (bid - 192) * 4 + q;
        float4 v = *(const float4*)(decWhh + j * H + kb * 4);
        wtD[kb * H3 + j] = v;
    } else {
        int r = (bid - 384) * 4 + q;               // fc row 0..73
        if (r < VOUT) {
            float4 v = *(const float4*)(fcW + r * H + kb * 4);
            fcT[kb * VOUT + r] = v;
        }
    }
}

// Precompute ALL input-side gate projections (parallel, no sequential dep):
//   items 0..31  : ENC_GI[t][j] = dot(enc_Wih[j], enc_emb[enc_input[t]]) + enc_bih[j]
//   items 32..105: DEC_GI[v][j] = dot(dec_Wih[j], dec_emb[v]) + dec_bih[j]
// One wave per output element; lane-parallel dot + shuffle reduce.
__global__ void prep_gi(const int*   __restrict__ enc_input,
                        const float* __restrict__ enc_emb,
                        const float* __restrict__ encWih,
                        const float* __restrict__ enc_bih,
                        const float* __restrict__ dec_emb,
                        const float* __restrict__ decWih,
                        const float* __restrict__ dec_bih,
                        float* __restrict__ ws) {
    int wid  = blockIdx.x * 4 + (threadIdx.x >> 6);
    int lane = threadIdx.x & 63;
    if (wid >= NITEMS * H3) return;
    int item = wid / H3;
    int j    = wid - item * H3;

    const float* x;
    const float* W;
    const float* b;
    float* out;
    if (item < L) {
        x   = enc_emb + enc_input[item] * H;
        W   = encWih + j * H;
        b   = enc_bih;
        out = ws + WS_EGI + item * H3 + j;
    } else {
        int v = item - L;
        x   = dec_emb + v * H;
        W   = decWih + j * H;
        b   = dec_bih;
        out = ws + WS_DGI + v * H3 + j;
    }
    float4 w  = ((const float4*)W)[lane];
    float4 xv = ((const float4*)x)[lane];
    float s = fmaf(w.x, xv.x, fmaf(w.y, xv.y, fmaf(w.z, xv.z, w.w * xv.w)));
    #pragma unroll
    for (int m = 1; m < 64; m <<= 1) s += __shfl_xor(s, m);
    if (lane == 0) *out = s + b[j];
}

__device__ __forceinline__ float sigmoidf_(float x) {
    return 1.0f / (1.0f + expf(-x));
}

// Sequential phase: one workgroup, 768 threads (thread = one gh row).
__global__ __launch_bounds__(768, 1) void seq_kernel(
        const float* __restrict__ enc_bhh,
        const float* __restrict__ dec_bhh,
        const float* __restrict__ fc_b,
        const float* __restrict__ ws,
        int* __restrict__ out) {
    __shared__ __align__(16) float h[H];
    __shared__ float gh[H3];
    __shared__ float logits[VOUT];
    __shared__ int s_tok, s_done;

    const float4* wtE = (const float4*)(ws + WS_WT_ENC);
    const float4* wtD = (const float4*)(ws + WS_WT_DEC);
    const float4* fcT = (const float4*)(ws + WS_FCT);
    const float*  egi = ws + WS_EGI;
    const float*  dgi = ws + WS_DGI;

    int tid = threadIdx.x;
    if (tid < H)     h[tid] = 0.0f;
    if (tid == 0)  { s_tok = 2; s_done = 0; }   // BOS=2
    if (tid < STEPS) out[tid] = 0;
    __syncthreads();

    const float4* hp = (const float4*)h;
    float bhhE = enc_bhh[tid];
    float bhhD = dec_bhh[tid];

    // ---------------- encoder: 32 steps ----------------
    for (int t = 0; t < L; ++t) {
        float acc = bhhE;
        #pragma unroll 16
        for (int kb = 0; kb < 64; ++kb) {
            float4 w  = wtE[kb * H3 + tid];
            float4 hv = hp[kb];
            acc = fmaf(w.x, hv.x, fmaf(w.y, hv.y, fmaf(w.z, hv.z, fmaf(w.w, hv.w, acc))));
        }
        gh[tid] = acc;
        __syncthreads();
        if (tid < H) {
            const float* gi = egi + t * H3;
            float r = sigmoidf_(gi[tid]       + gh[tid]);
            float z = sigmoidf_(gi[H + tid]   + gh[H + tid]);
            float n = tanhf    (gi[2*H + tid] + r * gh[2*H + tid]);
            h[tid] = (1.0f - z) * n + z * h[tid];
        }
        __syncthreads();
    }

    // ---------------- decoder: up to 20 steps ----------------
    for (int st = 0; st < STEPS; ++st) {
        if (s_done) break;                       // uniform (barrier-ordered)
        int tok = s_tok;

        float acc = bhhD;
        #pragma unroll 16
        for (int kb = 0; kb < 64; ++kb) {
            float4 w  = wtD[kb * H3 + tid];
            float4 hv = hp[kb];
            acc = fmaf(w.x, hv.x, fmaf(w.y, hv.y, fmaf(w.z, hv.z, fmaf(w.w, hv.w, acc))));
        }
        gh[tid] = acc;
        __syncthreads();

        if (tid < H) {
            const float* gi = dgi + tok * H3;
            float r = sigmoidf_(gi[tid]       + gh[tid]);
            float z = sigmoidf_(gi[H + tid]   + gh[H + tid]);
            float n = tanhf    (gi[2*H + tid] + r * gh[2*H + tid]);
            h[tid] = (1.0f - z) * n + z * h[tid];
        }
        __syncthreads();

        // logits = fc_W @ h2 + fc_b   (74 rows, thread-per-row, coalesced fcT)
        if (tid < VOUT) {
            float a = fc_b[tid];
            #pragma unroll 16
            for (int kb = 0; kb < 64; ++kb) {
                float4 w  = fcT[kb * VOUT + tid];
                float4 hv = hp[kb];
                a = fmaf(w.x, hv.x, fmaf(w.y, hv.y, fmaf(w.z, hv.z, fmaf(w.w, hv.w, a))));
            }
            logits[tid] = a;
        }
        __syncthreads();

        // argmax (first-index tie-break, matches jnp.argmax) on wave 0
        if (tid < 64) {
            float v  = logits[tid];
            int   bi = tid;
            if (tid < VOUT - 64) {
                float v2 = logits[64 + tid];
                if (v2 > v) { v = v2; bi = 64 + tid; }   // strict > keeps smaller idx on tie
            }
            #pragma unroll
            for (int m = 1; m < 64; m <<= 1) {
                float ov = __shfl_xor(v, m);
                int   ob = __shfl_xor(bi, m);
                if (ov > v || (ov == v && ob < bi)) { v = ov; bi = ob; }
            }
            if (tid == 0) {
                bool eos = (bi == 3);                    // EOS=3
                if (!eos) out[st] = bi;                  // EOS step records 0 (pre-zeroed)
                s_tok = bi;
                if (eos) s_done = 1;
            }
        }
        __syncthreads();
    }
}

extern "C" void kernel_launch(void* const* d_in, const int* in_sizes, int n_in,
                              void* d_out, int out_size, void* d_ws, size_t ws_size,
                              hipStream_t stream) {
    const int*   enc_input = (const int*)  d_in[0];
    const float* enc_emb   = (const float*)d_in[1];
    const float* enc_Wih   = (const float*)d_in[2];
    const float* enc_Whh   = (const float*)d_in[3];
    const float* enc_bih   = (const float*)d_in[4];
    const float* enc_bhh   = (const float*)d_in[5];
    const float* dec_emb   = (const float*)d_in[6];
    const float* dec_Wih   = (const float*)d_in[7];
    const float* dec_Whh   = (const float*)d_in[8];
    const float* dec_bih   = (const float*)d_in[9];
    const float* dec_bhh   = (const float*)d_in[10];
    const float* fc_W      = (const float*)d_in[11];
    const float* fc_b      = (const float*)d_in[12];
    float* ws = (float*)d_ws;
    int*  outp = (int*)d_out;

    hipLaunchKernelGGL(prep_transpose, dim3(403), dim3(256), 0, stream,
                       enc_Whh, dec_Whh, fc_W, ws);
    hipLaunchKernelGGL(prep_gi, dim3((NITEMS * H3 + 3) / 4), dim3(256), 0, stream,
                       enc_input, enc_emb, enc_Wih, enc_bih,
                       dec_emb, dec_Wih, dec_bih, ws);
    hipLaunchKernelGGL(seq_kernel, dim3(1), dim3(768), 0, stream,
                       enc_bhh, dec_bhh, fc_b, ws, outp);
}

// Round 2
// 192.503 us; speedup vs baseline: 2.0069x; 2.0069x over previous
//
#include <hip/hip_runtime.h>
#include <cmath>

#define H     256
#define H3    768
#define L     32
#define STEPS 20
#define VOUT  74
#define NWG   16
#define HW    16            // h rows per WG
#define ROWS  48            // gh rows per WG (3 gates x 16)
#define NITEMS (L + VOUT)   // 106

// ---- workspace layout (32-bit word offsets) ----
#define WS_CNT   0                      // int arrival counter
#define WS_HBUF  64                     // float [2][256] double-buffered h
#define WS_EGI   576                    // float [32][768]
#define WS_DGI   (576 + L * H3)         // float [74][768]  (25152)

__device__ __forceinline__ float sigmoidf_(float x) {
    return 1.0f / (1.0f + expf(-x));
}

// global gh-row for local row lr (0..47) of workgroup w:
// lr 0..15 -> r-gate rows j, 16..31 -> z rows H+j, 32..47 -> n rows 2H+j
__device__ __forceinline__ int growf(int w, int lr) {
    int j = w * HW + (lr & 15);
    return (lr < 16) ? j : (lr < 32 ? H + j : 2 * H + j);
}

// Prep: zero the barrier counter + h buffers, and precompute all input-side
// gate projections (encoder steps + all 74 decoder candidate tokens).
__global__ void prep(const int*   __restrict__ enc_input,
                     const float* __restrict__ enc_emb,
                     const float* __restrict__ encWih,
                     const float* __restrict__ enc_bih,
                     const float* __restrict__ dec_emb,
                     const float* __restrict__ decWih,
                     const float* __restrict__ dec_bih,
                     float* __restrict__ ws) {
    if (blockIdx.x == 0) {
        for (int k = threadIdx.x; k < 576; k += 256) ((int*)ws)[k] = 0;
    }
    int wid  = blockIdx.x * 4 + (threadIdx.x >> 6);
    int lane = threadIdx.x & 63;
    if (wid >= NITEMS * H3) return;
    int item = wid / H3;
    int j    = wid - item * H3;

    const float* x; const float* W; const float* b; float* out;
    if (item < L) {
        x = enc_emb + enc_input[item] * H;  W = encWih + j * H;
        b = enc_bih;                        out = ws + WS_EGI + item * H3 + j;
    } else {
        int v = item - L;
        x = dec_emb + v * H;                W = decWih + j * H;
        b = dec_bih;                        out = ws + WS_DGI + v * H3 + j;
    }
    float4 w  = ((const float4*)W)[lane];
    float4 xv = ((const float4*)x)[lane];
    float s = fmaf(w.x, xv.x, fmaf(w.y, xv.y, fmaf(w.z, xv.z, w.w * xv.w)));
    #pragma unroll
    for (int m = 1; m < 64; m <<= 1) s += __shfl_xor(s, m);
    if (lane == 0) *out = s + b[j];
}

// Sequential phase: 16 WGs, Whh in registers, h exchanged via global + counter.
__global__ __launch_bounds__(256, 1) void gru_seq(
        const float* __restrict__ enc_Whh, const float* __restrict__ enc_bhh,
        const float* __restrict__ dec_Whh, const float* __restrict__ dec_bhh,
        const float* __restrict__ fc_W,    const float* __restrict__ fc_b,
        float* __restrict__ ws, int* __restrict__ out) {
    __shared__ float hl[1040];          // 4 bank-padded copies of h (stride 260)
    __shared__ float fcL[VOUT * 260];   // fc_W, rows padded to 260
    __shared__ float fb[VOUT];
    __shared__ float gh_l[ROWS];
    __shared__ float gi_l[ROWS];
    __shared__ float log_l[VOUT];
    __shared__ int   s_tok, s_done;

    const int t = threadIdx.x;
    const int w = blockIdx.x;
    int* cnt = (int*)ws;
    float* hbuf = ws + WS_HBUF;

    // ---- one-time staging ----
    if (t == 0) { s_done = 0; s_tok = 2; }
    if (w == 0 && t < STEPS) out[t] = 0;
    for (int idx = t; idx < VOUT * H; idx += 256)
        fcL[(idx >> 8) * 260 + (idx & 255)] = fc_W[idx];
    if (t < VOUT) fb[t] = fc_b[t];

    const int p  = t & 3;          // k-chunk 0..3 (64 floats each)
    const int lr = t >> 2;         // local gh row 0..47 (t<192)
    const int g  = growf(w, lr < ROWS ? lr : 0);
    float4 wE[16], wD[16];
    float bhhE = 0.f, bhhD = 0.f;
    if (t < 4 * ROWS) {
        const float* eb = enc_Whh + g * H + p * 64;
        const float* db = dec_Whh + g * H + p * 64;
        #pragma unroll
        for (int i = 0; i < 16; ++i) {
            wE[i] = *(const float4*)(eb + 4 * i);
            wD[i] = *(const float4*)(db + 4 * i);
        }
        if (p == 0) { bhhE = enc_bhh[g]; bhhD = dec_bhh[g]; }
    }

    int tok = 2;  // BOS
    for (int s = 0; s <= L + STEPS; ++s) {      // 0..52
        // ---- wait for h^(s) (all WGs arrived for step s-1) ----
        if (t == 0) {
            while (__hip_atomic_load(cnt, __ATOMIC_ACQUIRE,
                                     __HIP_MEMORY_SCOPE_AGENT) < NWG * s)
                __builtin_amdgcn_s_sleep(1);
        }
        __syncthreads();
        // ---- load full h into 4 padded LDS copies ----
        {
            const unsigned* hsrc = (const unsigned*)(hbuf + (s & 1) * H);
            unsigned u = __hip_atomic_load(hsrc + t, __ATOMIC_RELAXED,
                                           __HIP_MEMORY_SCOPE_AGENT);
            float hv = __uint_as_float(u);
            hl[t] = hv; hl[260 + t] = hv; hl[520 + t] = hv; hl[780 + t] = hv;
        }
        __syncthreads();

        // ---- decoder: logits + argmax for step st = s-33 (uses h^(s)) ----
        if (s >= L + 1) {
            const int G = t >> 4, li = t & 15;
            const float* hb2 = hl + (li & 3) * 260 + li * 16;
            #pragma unroll
            for (int m = 0; m < 5; ++m) {
                int r = G + (m << 4);
                if (r < VOUT) {
                    const float* fr = fcL + r * 260 + li * 16;
                    float a = 0.f;
                    #pragma unroll
                    for (int c = 0; c < 4; ++c) {
                        float4 f  = *(const float4*)(fr + 4 * c);
                        float4 h4 = *(const float4*)(hb2 + 4 * c);
                        a = fmaf(f.x, h4.x, fmaf(f.y, h4.y,
                              fmaf(f.z, h4.z, fmaf(f.w, h4.w, a))));
                    }
                    a += __shfl_xor(a, 1); a += __shfl_xor(a, 2);
                    a += __shfl_xor(a, 4); a += __shfl_xor(a, 8);
                    if (li == 0) log_l[r] = a + fb[r];
                }
            }
            __syncthreads();
            if (t < 64) {
                float v = log_l[t]; int bi = t;
                if (t < VOUT - 64) {
                    float v2 = log_l[64 + t];
                    if (v2 > v) { v = v2; bi = 64 + t; }
                }
                #pragma unroll
                for (int m = 1; m < 64; m <<= 1) {
                    float ov = __shfl_xor(v, m);
                    int   ob = __shfl_xor(bi, m);
                    if (ov > v || (ov == v && ob < bi)) { v = ov; bi = ob; }
                }
                if (t == 0) {
                    bool eos = (bi == 3);
                    if (w == 0 && !eos) out[s - (L + 1)] = bi;
                    s_tok = bi;
                    if (eos) s_done = 1;
                }
            }
            __syncthreads();
            tok = s_tok;
            if (s_done || s == L + STEPS) break;
        }

        // ---- GRU step s: matvec (t<192) || gi prefetch (t>=192) ----
        if (t < 4 * ROWS) {
            float acc = (s < L) ? bhhE : bhhD;
            const float* hb = hl + p * 324;      // copy p, k-offset p*64
            if (s < L) {
                #pragma unroll
                for (int i = 0; i < 16; ++i) {
                    float4 h4 = *(const float4*)(hb + 4 * i);
                    acc = fmaf(wE[i].x, h4.x, fmaf(wE[i].y, h4.y,
                          fmaf(wE[i].z, h4.z, fmaf(wE[i].w, h4.w, acc))));
                }
            } else {
                #pragma unroll
                for (int i = 0; i < 16; ++i) {
                    float4 h4 = *(const float4*)(hb + 4 * i);
                    acc = fmaf(wD[i].x, h4.x, fmaf(wD[i].y, h4.y,
                          fmaf(wD[i].z, h4.z, fmaf(wD[i].w, h4.w, acc))));
                }
            }
            acc += __shfl_xor(acc, 1);
            acc += __shfl_xor(acc, 2);
            if (p == 0) gh_l[lr] = acc;
        } else if (t - 4 * ROWS < ROWS) {
            int lr2 = t - 4 * ROWS;
            const float* gib = (s < L) ? (ws + WS_EGI + s * H3)
                                       : (ws + WS_DGI + tok * H3);
            gi_l[lr2] = gib[growf(w, lr2)];
        }
        __syncthreads();

        // ---- gates -> h^(s+1) slice -> global ----
        if (t < HW) {
            int gj = w * HW + t;
            float r = sigmoidf_(gi_l[t]      + gh_l[t]);
            float z = sigmoidf_(gi_l[16 + t] + gh_l[16 + t]);
            float n = tanhf    (gi_l[32 + t] + r * gh_l[32 + t]);
            float hn = (1.f - z) * n + z * hl[gj];
            __hip_atomic_store((unsigned*)(hbuf + ((s + 1) & 1) * H + gj),
                               __float_as_uint(hn), __ATOMIC_RELAXED,
                               __HIP_MEMORY_SCOPE_AGENT);
        }
        __syncthreads();
        if (t == 0) {
            __threadfence();
            __hip_atomic_fetch_add(cnt, 1, __ATOMIC_ACQ_REL,
                                   __HIP_MEMORY_SCOPE_AGENT);
        }
    }
}

extern "C" void kernel_launch(void* const* d_in, const int* in_sizes, int n_in,
                              void* d_out, int out_size, void* d_ws, size_t ws_size,
                              hipStream_t stream) {
    const int*   enc_input = (const int*)  d_in[0];
    const float* enc_emb   = (const float*)d_in[1];
    const float* enc_Wih   = (const float*)d_in[2];
    const float* enc_Whh   = (const float*)d_in[3];
    const float* enc_bih   = (const float*)d_in[4];
    const float* enc_bhh   = (const float*)d_in[5];
    const float* dec_emb   = (const float*)d_in[6];
    const float* dec_Wih   = (const float*)d_in[7];
    const float* dec_Whh   = (const float*)d_in[8];
    const float* dec_bih   = (const float*)d_in[9];
    const float* dec_bhh   = (const float*)d_in[10];
    const float* fc_W      = (const float*)d_in[11];
    const float* fc_b      = (const float*)d_in[12];
    float* ws  = (float*)d_ws;
    int*  outp = (int*)d_out;

    hipLaunchKernelGGL(prep, dim3((NITEMS * H3 + 3) / 4), dim3(256), 0, stream,
                       enc_input, enc_emb, enc_Wih, enc_bih,
                       dec_emb, dec_Wih, dec_bih, ws);
    hipLaunchKernelGGL(gru_seq, dim3(NWG), dim3(256), 0, stream,
                       enc_Whh, enc_bhh, dec_Whh, dec_bhh, fc_W, fc_b,
                       ws, outp);
}

// Round 3
// 141.819 us; speedup vs baseline: 2.7241x; 1.3574x over previous
//
#include <hip/hip_runtime.h>
#include <cmath>

#define H     256
#define H3    768
#define L     32
#define STEPS 20
#define VOUT  74
#define NWG   16
#define HW    16            // h rows per WG
#define ROWS  48            // gh rows per WG (3 gates x 16)
#define NITEMS (L + VOUT)   // 106

// ---- workspace layout (32-bit word offsets) ----
// WS_HW: unsigned long long [2][256] packed (h_value<<32 | step_tag)
#define WS_HW    64                      // 1024 words (8B aligned)
#define WS_EGI   1088                    // float [32][768]
#define WS_DGI   (1088 + L * H3)         // float [74][768]

__device__ __forceinline__ float sigmoidf_(float x) {
    return 1.0f / (1.0f + expf(-x));
}

// global gh-row for local row lr (0..47) of workgroup w:
// lr 0..15 -> r-gate rows j, 16..31 -> z rows H+j, 32..47 -> n rows 2H+j
__device__ __forceinline__ int growf(int w, int lr) {
    int j = w * HW + (lr & 15);
    return (lr < 16) ? j : (lr < 32 ? H + j : 2 * H + j);
}

// Prep: zero the tagged h-exchange buffer, and precompute all input-side
// gate projections (encoder steps + all 74 decoder candidate tokens).
__global__ void prep(const int*   __restrict__ enc_input,
                     const float* __restrict__ enc_emb,
                     const float* __restrict__ encWih,
                     const float* __restrict__ enc_bih,
                     const float* __restrict__ dec_emb,
                     const float* __restrict__ decWih,
                     const float* __restrict__ dec_bih,
                     float* __restrict__ ws) {
    if (blockIdx.x == 0) {
        // zero words [0,1088): exchange buffer tags -> 0 == h^0 (value 0.0)
        for (int k = threadIdx.x; k < 1088; k += 256) ((int*)ws)[k] = 0;
    }
    int wid  = blockIdx.x * 4 + (threadIdx.x >> 6);
    int lane = threadIdx.x & 63;
    if (wid >= NITEMS * H3) return;
    int item = wid / H3;
    int j    = wid - item * H3;

    const float* x; const float* W; const float* b; float* out;
    if (item < L) {
        x = enc_emb + enc_input[item] * H;  W = encWih + j * H;
        b = enc_bih;                        out = ws + WS_EGI + item * H3 + j;
    } else {
        int v = item - L;
        x = dec_emb + v * H;                W = decWih + j * H;
        b = dec_bih;                        out = ws + WS_DGI + v * H3 + j;
    }
    float4 w  = ((const float4*)W)[lane];
    float4 xv = ((const float4*)x)[lane];
    float s = fmaf(w.x, xv.x, fmaf(w.y, xv.y, fmaf(w.z, xv.z, w.w * xv.w)));
    #pragma unroll
    for (int m = 1; m < 64; m <<= 1) s += __shfl_xor(s, m);
    if (lane == 0) *out = s + b[j];
}

// Sequential phase: 16 WGs, Whh in registers, h exchanged via packed
// (value,tag) 8-byte agent-scope atomics — one LLC round trip per step.
__global__ __launch_bounds__(256, 1) void gru_seq(
        const float* __restrict__ enc_Whh, const float* __restrict__ enc_bhh,
        const float* __restrict__ dec_Whh, const float* __restrict__ dec_bhh,
        const float* __restrict__ fc_W,    const float* __restrict__ fc_b,
        float* __restrict__ ws, int* __restrict__ out) {
    __shared__ float hl[1040];          // 4 bank-padded copies of h (stride 260)
    __shared__ float fcL[VOUT * 260];   // fc_W, rows padded to 260
    __shared__ float fb[VOUT];
    __shared__ float gh_l[ROWS];
    __shared__ float gi_l[ROWS];
    __shared__ float log_l[VOUT];
    __shared__ int   s_tok, s_done;

    const int t = threadIdx.x;
    const int w = blockIdx.x;
    unsigned long long* hw = (unsigned long long*)(ws + WS_HW);

    // ---- one-time staging ----
    if (t == 0) { s_done = 0; s_tok = 2; }
    if (w == 0 && t < STEPS) out[t] = 0;
    for (int idx = t; idx < VOUT * H; idx += 256)
        fcL[(idx >> 8) * 260 + (idx & 255)] = fc_W[idx];
    if (t < VOUT) fb[t] = fc_b[t];

    const int p  = t & 3;          // k-chunk 0..3 (64 floats each)
    const int lr = t >> 2;         // local gh row 0..47 (t<192)
    const int g  = growf(w, lr < ROWS ? lr : 0);
    float4 wE[16], wD[16];
    float bhhE = 0.f, bhhD = 0.f;
    if (t < 4 * ROWS) {
        const float* eb = enc_Whh + g * H + p * 64;
        const float* db = dec_Whh + g * H + p * 64;
        #pragma unroll
        for (int i = 0; i < 16; ++i) {
            wE[i] = *(const float4*)(eb + 4 * i);
            wD[i] = *(const float4*)(db + 4 * i);
        }
        if (p == 0) { bhhE = enc_bhh[g]; bhhD = dec_bhh[g]; }
    }

    int tok = 2;  // BOS
    for (int s = 0; s <= L + STEPS; ++s) {      // 0..52
        // ---- wait for h^(s): each thread polls its own packed word ----
        {
            unsigned long long u;
            const unsigned long long* src = hw + (s & 1) * H + t;
            do {
                u = __hip_atomic_load(src, __ATOMIC_RELAXED,
                                      __HIP_MEMORY_SCOPE_AGENT);
            } while ((unsigned)u != (unsigned)s);
            float hv = __uint_as_float((unsigned)(u >> 32));
            hl[t] = hv; hl[260 + t] = hv; hl[520 + t] = hv; hl[780 + t] = hv;
        }
        __syncthreads();

        // ---- decoder: logits + argmax for step st = s-33 (uses h^(s)) ----
        if (s >= L + 1) {
            const int G = t >> 4, li = t & 15;
            const float* hb2 = hl + (li & 3) * 260 + li * 16;
            #pragma unroll
            for (int m = 0; m < 5; ++m) {
                int r = G + (m << 4);
                if (r < VOUT) {
                    const float* fr = fcL + r * 260 + li * 16;
                    float a = 0.f;
                    #pragma unroll
                    for (int c = 0; c < 4; ++c) {
                        float4 f  = *(const float4*)(fr + 4 * c);
                        float4 h4 = *(const float4*)(hb2 + 4 * c);
                        a = fmaf(f.x, h4.x, fmaf(f.y, h4.y,
                              fmaf(f.z, h4.z, fmaf(f.w, h4.w, a))));
                    }
                    a += __shfl_xor(a, 1); a += __shfl_xor(a, 2);
                    a += __shfl_xor(a, 4); a += __shfl_xor(a, 8);
                    if (li == 0) log_l[r] = a + fb[r];
                }
            }
            __syncthreads();
            if (t < 64) {
                float v = log_l[t]; int bi = t;
                if (t < VOUT - 64) {
                    float v2 = log_l[64 + t];
                    if (v2 > v) { v = v2; bi = 64 + t; }
                }
                #pragma unroll
                for (int m = 1; m < 64; m <<= 1) {
                    float ov = __shfl_xor(v, m);
                    int   ob = __shfl_xor(bi, m);
                    if (ov > v || (ov == v && ob < bi)) { v = ov; bi = ob; }
                }
                if (t == 0) {
                    bool eos = (bi == 3);
                    if (w == 0 && !eos) out[s - (L + 1)] = bi;
                    s_tok = bi;
                    if (eos) s_done = 1;
                }
            }
            __syncthreads();
            tok = s_tok;
            if (s_done || s == L + STEPS) break;
        }

        // ---- GRU step s: matvec (t<192) || gi prefetch (t>=192) ----
        if (t < 4 * ROWS) {
            float acc = (s < L) ? bhhE : bhhD;
            const float* hb = hl + p * 324;      // copy p, k-offset p*64
            if (s < L) {
                #pragma unroll
                for (int i = 0; i < 16; ++i) {
                    float4 h4 = *(const float4*)(hb + 4 * i);
                    acc = fmaf(wE[i].x, h4.x, fmaf(wE[i].y, h4.y,
                          fmaf(wE[i].z, h4.z, fmaf(wE[i].w, h4.w, acc))));
                }
            } else {
                #pragma unroll
                for (int i = 0; i < 16; ++i) {
                    float4 h4 = *(const float4*)(hb + 4 * i);
                    acc = fmaf(wD[i].x, h4.x, fmaf(wD[i].y, h4.y,
                          fmaf(wD[i].z, h4.z, fmaf(wD[i].w, h4.w, acc))));
                }
            }
            acc += __shfl_xor(acc, 1);
            acc += __shfl_xor(acc, 2);
            if (p == 0) gh_l[lr] = acc;
        } else if (t - 4 * ROWS < ROWS) {
            int lr2 = t - 4 * ROWS;
            const float* gib = (s < L) ? (ws + WS_EGI + s * H3)
                                       : (ws + WS_DGI + tok * H3);
            gi_l[lr2] = gib[growf(w, lr2)];
        }
        __syncthreads();

        // ---- gates -> h^(s+1) slice: ONE packed 8B store, no fence ----
        if (t < HW) {
            int gj = w * HW + t;
            float r = sigmoidf_(gi_l[t]      + gh_l[t]);
            float z = sigmoidf_(gi_l[16 + t] + gh_l[16 + t]);
            float n = tanhf    (gi_l[32 + t] + r * gh_l[32 + t]);
            float hn = (1.f - z) * n + z * hl[gj];
            unsigned long long pk =
                ((unsigned long long)__float_as_uint(hn) << 32) |
                (unsigned)(s + 1);
            __hip_atomic_store(hw + ((s + 1) & 1) * H + gj, pk,
                               __ATOMIC_RELAXED, __HIP_MEMORY_SCOPE_AGENT);
        }
        // no trailing barrier needed: next-iteration LDS writes are ordered
        // by the post-matvec __syncthreads above; cross-WG ordering rides
        // entirely on the packed (value,tag) word.
    }
}

extern "C" void kernel_launch(void* const* d_in, const int* in_sizes, int n_in,
                              void* d_out, int out_size, void* d_ws, size_t ws_size,
                              hipStream_t stream) {
    const int*   enc_input = (const int*)  d_in[0];
    const float* enc_emb   = (const float*)d_in[1];
    const float* enc_Wih   = (const float*)d_in[2];
    const float* enc_Whh   = (const float*)d_in[3];
    const float* enc_bih   = (const float*)d_in[4];
    const float* enc_bhh   = (const float*)d_in[5];
    const float* dec_emb   = (const float*)d_in[6];
    const float* dec_Wih   = (const float*)d_in[7];
    const float* dec_Whh   = (const float*)d_in[8];
    const float* dec_bih   = (const float*)d_in[9];
    const float* dec_bhh   = (const float*)d_in[10];
    const float* fc_W      = (const float*)d_in[11];
    const float* fc_b      = (const float*)d_in[12];
    float* ws  = (float*)d_ws;
    int*  outp = (int*)d_out;

    hipLaunchKernelGGL(prep, dim3((NITEMS * H3 + 3) / 4), dim3(256), 0, stream,
                       enc_input, enc_emb, enc_Wih, enc_bih,
                       dec_emb, dec_Wih, dec_bih, ws);
    hipLaunchKernelGGL(gru_seq, dim3(NWG), dim3(256), 0, stream,
                       enc_Whh, enc_bhh, dec_Whh, dec_bhh, fc_W, fc_b,
                       ws, outp);
}